// Round 1
// baseline (305.808 us; speedup 1.0000x reference)
//
#include <hip/hip_runtime.h>

#define HH 1024
#define INW 512
#define BB 32
#define Z_MIN_C 0.001f
#define Z_RANGE_C 0.099f
#define E_H_C 0.5f

__device__ __forceinline__ float sigmoidf_(float v) {
    return 1.0f / (1.0f + __expf(-v));
}

// One block per output row j. 256 threads, each owns 4 consecutive k.
// Per-(j,k) params computed once, reused across all B=32 batches.
__global__ __launch_bounds__(256) void stp_fused(
    const float* __restrict__ x,    // (IN, B)
    const float* __restrict__ h,    // (B, H)
    const float* __restrict__ X,    // (B, H, H)
    const float* __restrict__ U,    // (B, H, H)
    const float* __restrict__ c_x,  // (H, H)
    const float* __restrict__ c_u,  // (H, H)
    const float* __restrict__ c_U,  // (H, H)
    const float* __restrict__ c_h,  // (H, 1)
    const float* __restrict__ w,    // (H, H)
    const float* __restrict__ p,    // (H, IN)
    const float* __restrict__ bias, // (H, 1)
    float* __restrict__ out)        // (B, H)
{
    const int j = blockIdx.x;
    const int t = threadIdx.x;
    const int lane = t & 63;
    const int wave = t >> 6;

    __shared__ float px_part[8][BB];   // p@x partials: seg x b
    __shared__ float rec_part[BB][4];  // rec partials: b x wave

    // ---- fused p@x prologue: pre[j,b] partial over 8 segments of 64 ----
    {
        const int b_id = t & 31;
        const int seg = t >> 5;
        float acc = 0.0f;
        const float* prow = p + j * INW + seg * 64;
        const float* xcol = x + seg * 64 * BB + b_id;
        #pragma unroll 8
        for (int i = 0; i < 64; ++i)
            acc += prow[i] * xcol[i * BB];
        px_part[seg][b_id] = acc;
    }

    // ---- per-k parameters for row j (computed once, reused over b) ----
    const int k0 = t * 4;
    float4 cx4 = *(const float4*)(c_x + j * HH + k0);
    float4 cu4 = *(const float4*)(c_u + j * HH + k0);
    float4 cC4 = *(const float4*)(c_U + j * HH + k0);
    float4 wv4 = *(const float4*)(w + j * HH + k0);
    const float* cxv = &cx4.x;
    const float* cuv = &cu4.x;
    const float* cCv = &cC4.x;
    const float* wvv = &wv4.x;

    float zx[4], ozx[4], Acoef[4], ozu[4], Uc[4], wr[4];
    #pragma unroll
    for (int c = 0; c < 4; ++c) {
        float zxx = Z_MIN_C + Z_RANGE_C * sigmoidf_(cxv[c]);
        float zuu = Z_MIN_C + Z_RANGE_C * sigmoidf_(cuv[c]);
        float ucc = 0.9f * sigmoidf_(cCv[c]);
        zx[c] = zxx;
        ozx[c] = 1.0f - zxx;
        ozu[c] = 1.0f - zuu;
        Uc[c] = ucc;
        Acoef[c] = ucc * zuu;
        wr[c] = wvv[c];
    }

    // ---- main loop over batches: stream X,U rows ----
    for (int b = 0; b < BB; ++b) {
        const float hj = h[b * HH + j];
        float4 hk4 = *(const float4*)(h + b * HH + k0);
        const int rowbase = (b * HH + j) * HH;  // < 2^25, fits int
        float4 Xv4 = *(const float4*)(X + rowbase + k0);
        float4 Uv4 = *(const float4*)(U + rowbase + k0);
        const float* Xv = &Xv4.x;
        const float* Uv = &Uv4.x;
        const float* hk = &hk4.x;

        float s = 0.0f;
        #pragma unroll
        for (int c = 0; c < 4; ++c) {
            // X_new = z_x + (1-z_x)*X - U*(X*hj)
            float Xn = fmaf(ozx[c], Xv[c], zx[c]);
            Xn = fmaf(-Uv[c], Xv[c] * hj, Xn);
            // U_new = Ucap*z_u + (1-z_u)*U + Ucap*hj*(1-U), clamped [Ucap, 1]
            float Un = fmaf(ozu[c], Uv[c], Acoef[c]);
            Un = fmaf(Uc[c] * hj, 1.0f - Uv[c], Un);
            Un = fminf(fmaxf(Un, Uc[c]), 1.0f);
            // W*h[b,k] contribution
            s = fmaf(wr[c] * hk[c], Un * Xn, s);
        }

        // wave(64)-level reduction
        #pragma unroll
        for (int off = 32; off > 0; off >>= 1)
            s += __shfl_xor(s, off);
        if (lane == 0) rec_part[b][wave] = s;
    }
    __syncthreads();

    // ---- finalize: thread t = batch b ----
    if (t < BB) {
        float rec = rec_part[t][0] + rec_part[t][1] + rec_part[t][2] + rec_part[t][3];
        float px = 0.0f;
        #pragma unroll
        for (int sgi = 0; sgi < 8; ++sgi) px += px_part[sgi][t];
        float pre = rec + px + bias[j];
        float zh = E_H_C * sigmoidf_(c_h[j]);
        float hv = h[t * HH + j];
        out[t * HH + j] = (1.0f - zh) * hv + zh * sigmoidf_(pre);
    }
}

extern "C" void kernel_launch(void* const* d_in, const int* in_sizes, int n_in,
                              void* d_out, int out_size, void* d_ws, size_t ws_size,
                              hipStream_t stream) {
    const float* x   = (const float*)d_in[0];
    const float* h   = (const float*)d_in[1];
    const float* X   = (const float*)d_in[2];
    const float* U   = (const float*)d_in[3];
    const float* c_x = (const float*)d_in[4];
    const float* c_u = (const float*)d_in[5];
    const float* c_U = (const float*)d_in[6];
    const float* c_h = (const float*)d_in[7];
    const float* w   = (const float*)d_in[8];
    const float* p   = (const float*)d_in[9];
    const float* b   = (const float*)d_in[10];
    float* out = (float*)d_out;

    stp_fused<<<HH, 256, 0, stream>>>(x, h, X, U, c_x, c_u, c_U, c_h, w, p, b, out);
}